// Round 14
// baseline (84.722 us; speedup 1.0000x reference)
//
#include <hip/hip_runtime.h>
#include <hip/hip_fp16.h>
#include <math.h>

#define EH   65536
#define LAMF 5.0f
#define SVF  0.36787944117144233f   // exp(-0.2*5) = exp(-1)

typedef __bf16 bf16x8 __attribute__((ext_vector_type(8)));
typedef float  f32x4  __attribute__((ext_vector_type(4)));
typedef _Float16 f16x2 __attribute__((ext_vector_type(2)));

__device__ __forceinline__ float sigmoidf_(float x) { return 1.0f / (1.0f + expf(-x)); }

__device__ __forceinline__ void cvt1(float v, ushort& h, ushort& l) {
    __bf16 bh = (__bf16)v;
    h = __builtin_bit_cast(ushort, bh);
    __bf16 bl = (__bf16)(v - (float)bh);
    l = __builtin_bit_cast(ushort, bl);
}

__device__ __forceinline__ f16x2 u2h(uint u) { return __builtin_bit_cast(f16x2, u); }
__device__ __forceinline__ float2 h2f2u(uint u) {
    __half2 h = __builtin_bit_cast(__half2, u);
    return __half22float2(h);
}

// ============ unified 64x64 MFMA GEMM, BK=64, split-bf16, reg-prefetch ======
// MODE 0: encoder partial  P[z] = x @ W_enc(k-slice, z=0..7)  grid(8,8,8), 4 iters
// MODE 1: C45|C23 fused    [h@Wnbr | h@Wself | h@W1a | h@W1b] grid(20,8),  8 iters
// MODE 2: agg + epilogue   outm = relu(ew@Hn + Hs + b_mp)     grid(8,8),   4 iters
#define LSTR2 72   // LDS row stride in ushorts (144B, 16B-aligned rows)
template<int MODE>
__global__ __launch_bounds__(256) void gemm64(
    const float* __restrict__ Aa, const float* __restrict__ Ab,
    const float* __restrict__ B0, const float* __restrict__ B1,
    const float* __restrict__ B2,
    const float* __restrict__ HsC45, const float* __restrict__ bmp,
    float* __restrict__ C0, float* __restrict__ C1)
{
    __shared__ ushort As_hi[64*LSTR2], As_lo[64*LSTR2];
    __shared__ ushort Bs_hi[64*LSTR2], Bs_lo[64*LSTR2];
    const int tid = threadIdx.x;
    const int row0 = blockIdx.y * 64;

    const float* Ap = Aa; int lda, arow0 = row0, ak = 0;
    const float* Bp; int ldb, kb = 0, bcol0;
    float* Cp; int ldc, ccol0;
    int KS;

    if (MODE == 0) {
        KS = 256; lda = 2048; ak = blockIdx.z * 256;
        Bp = B0; ldb = 512; kb = blockIdx.z * 256; bcol0 = blockIdx.x * 64;
        Cp = C0 + blockIdx.z * 262144; ldc = 512; ccol0 = bcol0;
    } else if (MODE == 1) {
        KS = 512; lda = 512;
        int cb = blockIdx.x;
        if (cb < 8)       { Bp=B0; ldb=512; kb=0;   bcol0=cb*64;        Cp=C0; ldc=1024; ccol0=cb*64; }
        else if (cb < 16) { Bp=B1; ldb=512; kb=0;   bcol0=(cb-8)*64;    Cp=C0; ldc=1024; ccol0=512+(cb-8)*64; }
        else if (cb < 18) { Bp=B2; ldb=128; kb=0;   bcol0=(cb-16)*64;   Cp=C1; ldc=256;  ccol0=(cb-16)*64; }
        else              { Bp=B2; ldb=128; kb=512; bcol0=(cb-18)*64;   Cp=C1; ldc=256;  ccol0=128+(cb-18)*64; }
    } else {
        KS = 256; lda = 256;
        if (row0 < 256) { Ap = Aa; arow0 = row0;       kb = 256; }
        else            { Ap = Ab; arow0 = row0 - 256; kb = 0; }
        Bp = B0; ldb = 1024; bcol0 = blockIdx.x * 64;
        Cp = C0; ldc = 512; ccol0 = bcol0;
    }

    // A-stage map: each thread 16 consecutive floats of one row (4 x float4)
    const int arow = tid >> 2, kq = (tid & 3) * 16;
    // B-stage map: 2 k-rows x 8 cols per thread
    const int kr = (tid & 31) * 2, nc0 = (tid >> 5) * 8;
    const float* aptr = Ap + (size_t)(arow0 + arow) * lda + ak + kq;
    const float* bptr = Bp + (size_t)(kb + kr) * ldb + bcol0 + nc0;

    f32x4 acc[2][2] = {};
    const int lane = tid & 63, w = tid >> 6;
    const int qr = (w >> 1) * 32, qc = (w & 1) * 32;
    const int fr = lane & 15, kg = (lane >> 4) * 8;

    float4 pa[4], pb[4];
    #pragma unroll
    for (int q = 0; q < 4; ++q) pa[q] = *(const float4*)(aptr + q * 4);
    pb[0] = *(const float4*)bptr;         pb[1] = *(const float4*)(bptr + 4);
    pb[2] = *(const float4*)(bptr + ldb); pb[3] = *(const float4*)(bptr + ldb + 4);

    for (int k0 = 0; k0 < KS; k0 += 64) {
        // ---- store staged tile (cvt fp32 -> hi/lo bf16)
        {
            #pragma unroll
            for (int q = 0; q < 4; ++q) {
                ushort4 h4, l4;
                cvt1(pa[q].x,h4.x,l4.x); cvt1(pa[q].y,h4.y,l4.y);
                cvt1(pa[q].z,h4.z,l4.z); cvt1(pa[q].w,h4.w,l4.w);
                *(ushort4*)&As_hi[arow*LSTR2 + kq + q*4] = h4;
                *(ushort4*)&As_lo[arow*LSTR2 + kq + q*4] = l4;
            }
            float r0[8] = {pb[0].x, pb[0].y, pb[0].z, pb[0].w,
                           pb[1].x, pb[1].y, pb[1].z, pb[1].w};
            float r1[8] = {pb[2].x, pb[2].y, pb[2].z, pb[2].w,
                           pb[3].x, pb[3].y, pb[3].z, pb[3].w};
            #pragma unroll
            for (int j = 0; j < 8; ++j) {
                ushort ha, la, hb, lb;
                cvt1(r0[j], ha, la); cvt1(r1[j], hb, lb);
                *(uint*)&Bs_hi[(nc0+j)*LSTR2 + kr] = (uint)ha | ((uint)hb << 16);
                *(uint*)&Bs_lo[(nc0+j)*LSTR2 + kr] = (uint)la | ((uint)lb << 16);
            }
        }
        __syncthreads();
        if (k0 + 64 < KS) {   // prefetch next tile (overlaps MFMA + barrier)
            #pragma unroll
            for (int q = 0; q < 4; ++q) pa[q] = *(const float4*)(aptr + k0 + 64 + q * 4);
            const float* bp2 = bptr + (size_t)(k0 + 64) * ldb;
            pb[0] = *(const float4*)bp2;         pb[1] = *(const float4*)(bp2 + 4);
            pb[2] = *(const float4*)(bp2 + ldb); pb[3] = *(const float4*)(bp2 + ldb + 4);
        }
        #pragma unroll
        for (int kk = 0; kk < 2; ++kk) {
            bf16x8 ah[2], al[2], bh[2], bl[2];
            #pragma unroll
            for (int m = 0; m < 2; ++m) {
                int r = (qr + m*16 + fr) * LSTR2 + kg + kk * 32;
                ah[m] = *(const bf16x8*)&As_hi[r];
                al[m] = *(const bf16x8*)&As_lo[r];
            }
            #pragma unroll
            for (int n = 0; n < 2; ++n) {
                int r = (qc + n*16 + fr) * LSTR2 + kg + kk * 32;
                bh[n] = *(const bf16x8*)&Bs_hi[r];
                bl[n] = *(const bf16x8*)&Bs_lo[r];
            }
            #pragma unroll
            for (int m = 0; m < 2; ++m)
                #pragma unroll
                for (int n = 0; n < 2; ++n) {
                    acc[m][n] = __builtin_amdgcn_mfma_f32_16x16x32_bf16(ah[m], bh[n], acc[m][n], 0, 0, 0);
                    acc[m][n] = __builtin_amdgcn_mfma_f32_16x16x32_bf16(ah[m], bl[n], acc[m][n], 0, 0, 0);
                    acc[m][n] = __builtin_amdgcn_mfma_f32_16x16x32_bf16(al[m], bh[n], acc[m][n], 0, 0, 0);
                }
        }
        __syncthreads();
    }

    const int rbase = (lane >> 4) * 4;
    #pragma unroll
    for (int m = 0; m < 2; ++m)
        #pragma unroll
        for (int n = 0; n < 2; ++n)
            #pragma unroll
            for (int r = 0; r < 4; ++r) {
                int gr = row0 + qr + m*16 + rbase + r;
                int gc = ccol0 + qc + n*16 + (lane & 15);
                float v = acc[m][n][r];
                if (MODE == 2) {
                    v += HsC45[(size_t)gr * 1024 + 512 + gc] + bmp[gc];
                    v = fmaxf(v, 0.f);
                }
                Cp[(size_t)gr * ldc + gc] = v;
            }
}

// ============ encoder split-K reduce: h = relu(sum_z P[z] + bias) ===========
__global__ __launch_bounds__(256) void enc_reduce(const float* __restrict__ P,
    const float* __restrict__ bias, float* __restrict__ h)
{
    int e = (blockIdx.x * 256 + threadIdx.x) * 4;
    int col = e & 511;
    float4 s = *(const float4*)&P[e];
    #pragma unroll
    for (int z = 1; z < 8; ++z) {
        float4 v = *(const float4*)&P[e + z * 262144];
        s.x += v.x; s.y += v.y; s.z += v.z; s.w += v.w;
    }
    float4 b = *(const float4*)&bias[col];
    float4 o;
    o.x = fmaxf(s.x + b.x, 0.f);
    o.y = fmaxf(s.y + b.y, 0.f);
    o.z = fmaxf(s.z + b.z, 0.f);
    o.w = fmaxf(s.w + b.w, 0.f);
    *(float4*)&h[e] = o;
}

// ============ per-edge ew + iou (geo MLP inlined, b128 LDS reads) ===========
__global__ __launch_bounds__(256) void edge_geo_kernel(
    const float* __restrict__ C23, const float* __restrict__ coords,
    const float* __restrict__ geo_W1, const float* __restrict__ geo_b1,
    const float* __restrict__ app_b1, const float* __restrict__ app_w2,
    const float* __restrict__ app_b2, const float* __restrict__ geo_w2,
    const float* __restrict__ geo_b2, const float* __restrict__ aff_w,
    const float* __restrict__ aff_b, const float* __restrict__ co,
    const float* __restrict__ gt, float* __restrict__ outp,
    float* __restrict__ ewT0, float* __restrict__ ew2, float* __restrict__ iou1)
{
    __shared__ __align__(16) float sA[16][132], sB[16][132];
    __shared__ __align__(16) float sGA[16][68], sGB[16][68];
    __shared__ __align__(16) float sw2[128], sgw2[64];
    __shared__ float sgw[8][64], sgb[64], scs[16][4], scd[16][4];
    const int tid = threadIdx.x;
    const int half = blockIdx.z;
    const int t0 = blockIdx.y * 16, d0 = blockIdx.x * 16;
    const int sbase = half ? (256 + d0) : t0;   // source-node rows
    const int dbase = half ? t0 : (256 + d0);   // dest-node rows

    // fold gt-copy + scalar consts into half=1 blocks (independent early work)
    if (half == 1) {
        int bid = blockIdx.y * 16 + blockIdx.x;     // 0..255
        if (tid < 64) {
            int o = bid * 256 + tid * 4;
            *(float4*)&outp[EH + o] = *(const float4*)&gt[o];
        }
        if (bid == 0 && tid == 64) {
            outp[2 * EH]     = 256.0f;
            outp[2 * EH + 1] = 256.0f;
        }
    }

    for (int i = tid; i < 16 * 32; i += 256) {
        int rr = i >> 5, c4 = (i & 31) << 2;
        float4 va = *(const float4*)&C23[(sbase + rr) * 256 + c4];
        sA[rr][c4] = va.x; sA[rr][c4+1] = va.y; sA[rr][c4+2] = va.z; sA[rr][c4+3] = va.w;
        float4 vb = *(const float4*)&C23[(dbase + rr) * 256 + 128 + c4];
        float4 b1 = *(const float4*)&app_b1[c4];
        sB[rr][c4] = vb.x + b1.x; sB[rr][c4+1] = vb.y + b1.y;
        sB[rr][c4+2] = vb.z + b1.z; sB[rr][c4+3] = vb.w + b1.w;
    }
    for (int i = tid; i < 512; i += 256) sgw[i >> 6][i & 63] = geo_W1[i];
    if (tid < 64) sgb[tid] = geo_b1[tid];
    else if (tid < 192) sw2[tid - 64] = app_w2[tid - 64];
    else sgw2[tid - 192] = geo_w2[tid - 192];
    if (tid < 64) scs[tid >> 2][tid & 3] = coords[(sbase + (tid >> 2)) * 4 + (tid & 3)];
    else if (tid < 128) { int i = tid - 64; scd[i >> 2][i & 3] = coords[(dbase + (i >> 2)) * 4 + (i & 3)]; }
    __syncthreads();
    for (int v = tid; v < 2048; v += 256) {
        int hh = v >> 10, rr = (v >> 6) & 15, j = v & 63;
        if (hh == 0) {
            sGA[rr][j] = scs[rr][0]*sgw[0][j] + scs[rr][1]*sgw[1][j]
                       + scs[rr][2]*sgw[2][j] + scs[rr][3]*sgw[3][j] + sgb[j];
        } else {
            sGB[rr][j] = scd[rr][0]*sgw[4][j] + scd[rr][1]*sgw[5][j]
                       + scd[rr][2]*sgw[6][j] + scd[rr][3]*sgw[7][j];
        }
    }
    __syncthreads();
    const int tx = tid & 15, ty = tid >> 4;
    const int si = half ? tx : ty;
    const int di = half ? ty : tx;
    float acc1 = 0.f;
    #pragma unroll
    for (int j4 = 0; j4 < 128; j4 += 4) {
        float4 a = *(const float4*)&sA[si][j4];
        float4 b = *(const float4*)&sB[di][j4];
        float4 wv = *(const float4*)&sw2[j4];
        acc1 += fmaxf(a.x + b.x, 0.f) * wv.x + fmaxf(a.y + b.y, 0.f) * wv.y
              + fmaxf(a.z + b.z, 0.f) * wv.z + fmaxf(a.w + b.w, 0.f) * wv.w;
    }
    float x1 = sigmoidf_(acc1 + app_b2[0]);
    float acc2 = 0.f;
    #pragma unroll
    for (int j4 = 0; j4 < 64; j4 += 4) {
        float4 a = *(const float4*)&sGA[si][j4];
        float4 b = *(const float4*)&sGB[di][j4];
        float4 wv = *(const float4*)&sgw2[j4];
        acc2 += fmaxf(a.x + b.x, 0.f) * wv.x + fmaxf(a.y + b.y, 0.f) * wv.y
              + fmaxf(a.z + b.z, 0.f) * wv.z + fmaxf(a.w + b.w, 0.f) * wv.w;
    }
    float x2 = sigmoidf_(acc2 + geo_b2[0]);
    float e = sigmoidf_(x1 * aff_w[0] + x2 * aff_w[1] + aff_b[0]);
    const int t = t0 + ty, d = d0 + tx;
    if (half) ew2[t * 256 + d] = e;
    else      ewT0[d * 256 + t] = e;
    if (half == 0) {
        float4 a = *(const float4*)&co[t * 4];
        float4 b = *(const float4*)&co[(256 + d) * 4];
        float ltx = fmaxf(a.x, b.x), lty = fmaxf(a.y, b.y);
        float rbx = fminf(a.z, b.z), rby = fminf(a.w, b.w);
        float w  = fmaxf(rbx - ltx, 0.f), hh = fmaxf(rby - lty, 0.f);
        float inter = w * hh;
        float areaA = (a.z - a.x) * (a.w - a.y);
        float areaB = (b.z - b.x) * (b.w - b.y);
        iou1[t * 256 + d] = inter / (areaA + areaB - inter + 1e-6f);
    }
}

// ============ gram 32x32, BK=64 (8 iters), norms + fin/exp epilogue =========
__global__ __launch_bounds__(256) void gram32(const float* __restrict__ outm,
    const float* __restrict__ iou, const float* __restrict__ finw,
    const float* __restrict__ finb, __half* __restrict__ Mh)
{
    __shared__ ushort As_hi[32*LSTR2], As_lo[32*LSTR2];
    __shared__ ushort Bs_hi[32*LSTR2], Bs_lo[32*LSTR2];
    __shared__ float snA[32], snB[32];
    const int tid = threadIdx.x;
    const int t0 = blockIdx.y * 32, d0 = blockIdx.x * 32;
    const float* Asrc = outm;
    const float* Bsrc = outm + (size_t)256 * 512;

    // stage map: each thread 8 consecutive floats of one row (2 x float4)
    const int arow = tid >> 3, kq = (tid & 7) * 8;
    const float* aptr = Asrc + (size_t)(t0 + arow) * 512 + kq;
    const float* bptr = Bsrc + (size_t)(d0 + arow) * 512 + kq;

    f32x4 acc = {};
    float ssA = 0.f, ssB = 0.f;
    const int lane = tid & 63, w = tid >> 6;
    const int qr = (w >> 1) * 16, qc = (w & 1) * 16;
    const int fr = lane & 15, kg = (lane >> 4) * 8;

    float4 pa0 = *(const float4*)aptr, pa1 = *(const float4*)(aptr + 4);
    float4 pb0 = *(const float4*)bptr, pb1 = *(const float4*)(bptr + 4);

    for (int k0 = 0; k0 < 512; k0 += 64) {
        ssA += pa0.x*pa0.x + pa0.y*pa0.y + pa0.z*pa0.z + pa0.w*pa0.w
             + pa1.x*pa1.x + pa1.y*pa1.y + pa1.z*pa1.z + pa1.w*pa1.w;
        ssB += pb0.x*pb0.x + pb0.y*pb0.y + pb0.z*pb0.z + pb0.w*pb0.w
             + pb1.x*pb1.x + pb1.y*pb1.y + pb1.z*pb1.z + pb1.w*pb1.w;
        {
            ushort4 h4, l4;
            cvt1(pa0.x,h4.x,l4.x); cvt1(pa0.y,h4.y,l4.y); cvt1(pa0.z,h4.z,l4.z); cvt1(pa0.w,h4.w,l4.w);
            *(ushort4*)&As_hi[arow*LSTR2 + kq] = h4;
            *(ushort4*)&As_lo[arow*LSTR2 + kq] = l4;
            cvt1(pa1.x,h4.x,l4.x); cvt1(pa1.y,h4.y,l4.y); cvt1(pa1.z,h4.z,l4.z); cvt1(pa1.w,h4.w,l4.w);
            *(ushort4*)&As_hi[arow*LSTR2 + kq + 4] = h4;
            *(ushort4*)&As_lo[arow*LSTR2 + kq + 4] = l4;
            cvt1(pb0.x,h4.x,l4.x); cvt1(pb0.y,h4.y,l4.y); cvt1(pb0.z,h4.z,l4.z); cvt1(pb0.w,h4.w,l4.w);
            *(ushort4*)&Bs_hi[arow*LSTR2 + kq] = h4;
            *(ushort4*)&Bs_lo[arow*LSTR2 + kq] = l4;
            cvt1(pb1.x,h4.x,l4.x); cvt1(pb1.y,h4.y,l4.y); cvt1(pb1.z,h4.z,l4.z); cvt1(pb1.w,h4.w,l4.w);
            *(ushort4*)&Bs_hi[arow*LSTR2 + kq + 4] = h4;
            *(ushort4*)&Bs_lo[arow*LSTR2 + kq + 4] = l4;
        }
        __syncthreads();
        if (k0 + 64 < 512) {
            pa0 = *(const float4*)(aptr + k0 + 64);
            pa1 = *(const float4*)(aptr + k0 + 68);
            pb0 = *(const float4*)(bptr + k0 + 64);
            pb1 = *(const float4*)(bptr + k0 + 68);
        }
        #pragma unroll
        for (int kk = 0; kk < 2; ++kk) {
            bf16x8 ah, al, bh, bl;
            {
                int r = (qr + fr) * LSTR2 + kg + kk * 32;
                ah = *(const bf16x8*)&As_hi[r]; al = *(const bf16x8*)&As_lo[r];
            }
            {
                int r = (qc + fr) * LSTR2 + kg + kk * 32;
                bh = *(const bf16x8*)&Bs_hi[r]; bl = *(const bf16x8*)&Bs_lo[r];
            }
            acc = __builtin_amdgcn_mfma_f32_16x16x32_bf16(ah, bh, acc, 0, 0, 0);
            acc = __builtin_amdgcn_mfma_f32_16x16x32_bf16(ah, bl, acc, 0, 0, 0);
            acc = __builtin_amdgcn_mfma_f32_16x16x32_bf16(al, bh, acc, 0, 0, 0);
        }
        __syncthreads();
    }
    // reduce sumsq across the 8 threads sharing a row (consecutive lanes)
    ssA += __shfl_xor(ssA, 1); ssA += __shfl_xor(ssA, 2); ssA += __shfl_xor(ssA, 4);
    ssB += __shfl_xor(ssB, 1); ssB += __shfl_xor(ssB, 2); ssB += __shfl_xor(ssB, 4);
    if ((tid & 7) == 0) { snA[arow] = ssA; snB[arow] = ssB; }
    __syncthreads();
    const float fw0 = finw[0], fw1 = finw[1], fb = finb[0];
    const int rbase = (lane >> 4) * 4, lc = qc + (lane & 15);
    #pragma unroll
    for (int r = 0; r < 4; ++r) {
        int lr = qr + rbase + r;
        float na = fmaxf(sqrtf(snA[lr]), 1e-6f);
        float nb = fmaxf(sqrtf(snB[lc]), 1e-6f);
        int t = t0 + lr, d = d0 + lc;
        float cosv = acc[r] / (na * nb);
        float fin = sigmoidf_(cosv * fw0 + iou[t * 256 + d] * fw1 + fb);
        Mh[t * 256 + d] = __float2half(expf(fin * LAMF));
    }
}

// ============ Sinkhorn4f: reg-resident M, fdot2, FUSED final output =========
// row-view: thread (row=tid>>2, sub4=tid&3) holds M[row][sub4*64..+64) = 8 uint4
// col-view: thread (cg=tid>>5, sub32=tid&31) holds rows {2*sub32+64p,+1} x cols
//           [8cg..+8). After 8 iters, out = M0*r*c written from row-view regs.
__global__ __launch_bounds__(1024, 4) void sinkhorn4f(const __half* __restrict__ Mh,
    float* __restrict__ out)
{
    __shared__ __align__(16) float r_f[256], c_f[256];
    __shared__ float red[16];
    __shared__ __half r_h[256], c_h[256];
    const int tid = threadIdx.x;
    const int row = tid >> 2, sub4 = tid & 3;
    const int cg = tid >> 5, sub32 = tid & 31;

    const uint4* gm = (const uint4*)Mh;            // [256 rows][32 uint4]
    uint4 mr[8];                                   // row-view
    #pragma unroll
    for (int j = 0; j < 8; ++j) mr[j] = gm[row * 32 + sub4 * 8 + j];
    uint4 mca[4], mcb[4];                          // col-view row-pairs
    #pragma unroll
    for (int p = 0; p < 4; ++p) {
        int rp = 2 * sub32 + 64 * p;
        mca[p] = gm[rp * 32 + cg];
        mcb[p] = gm[(rp + 1) * 32 + cg];
    }
    if (tid < 256) { c_f[tid] = 1.0f; c_h[tid] = __float2half(1.0f); }
    if (tid == 0) red[1] = 1.0f / SVF;             // makes c256 = 1 at it=0
    __syncthreads();

    const int b4 = (sub32 >> 4) & 1, b3 = (sub32 >> 3) & 1, b2 = (sub32 >> 2) & 1;

    for (int it = 0; it < 8; ++it) {
        // ======== ROW phase: r[t] = 1/(sum_d M[t][d] c[d] + SVF*c256)
        float c256 = 1.0f / (SVF * red[1]);
        float a0 = 0.f, a1 = 0.f, a2 = 0.f, a3 = 0.f;
        {
            uint4 cu[4];
            #pragma unroll
            for (int j = 0; j < 4; ++j) cu[j] = *(const uint4*)&c_h[sub4 * 64 + j * 8];
            #pragma unroll
            for (int j = 0; j < 4; ++j) {
                a0 = __builtin_amdgcn_fdot2(u2h(mr[j].x), u2h(cu[j].x), a0, false);
                a1 = __builtin_amdgcn_fdot2(u2h(mr[j].y), u2h(cu[j].y), a1, false);
                a2 = __builtin_amdgcn_fdot2(u2h(mr[j].z), u2h(cu[j].z), a2, false);
                a3 = __builtin_amdgcn_fdot2(u2h(mr[j].w), u2h(cu[j].w), a3, false);
            }
            #pragma unroll
            for (int j = 0; j < 4; ++j) cu[j] = *(const uint4*)&c_h[sub4 * 64 + 32 + j * 8];
            #pragma unroll
            for (int j = 0; j < 4; ++j) {
                a0 = __builtin_amdgcn_fdot2(u2h(mr[4+j].x), u2h(cu[j].x), a0, false);
                a1 = __builtin_amdgcn_fdot2(u2h(mr[4+j].y), u2h(cu[j].y), a1, false);
                a2 = __builtin_amdgcn_fdot2(u2h(mr[4+j].z), u2h(cu[j].z), a2, false);
                a3 = __builtin_amdgcn_fdot2(u2h(mr[4+j].w), u2h(cu[j].w), a3, false);
            }
        }
        float acc = (a0 + a1) + (a2 + a3);
        acc += __shfl_xor(acc, 1); acc += __shfl_xor(acc, 2);
        if (tid < 64) {      // Sc = sum c + c256
            float s = c_f[tid] + c_f[tid + 64] + c_f[tid + 128] + c_f[tid + 192];
            #pragma unroll
            for (int o = 32; o; o >>= 1) s += __shfl_down(s, o);
            if (tid == 0) red[0] = s + c256;
        }
        if (sub4 == 0) {
            float v = 1.0f / (acc + SVF * c256);
            r_f[row] = v; r_h[row] = __float2half(v);
        }
        __syncthreads();

        // ======== COL phase: c[d] = 1/(sum_t M[t][d] r[t] + SVF*r256)
        float r256 = 1.0f / (SVF * red[0]);
        float b[8] = {0.f,0.f,0.f,0.f,0.f,0.f,0.f,0.f};
        #pragma unroll
        for (int p = 0; p < 4; ++p) {
            f16x2 rp = u2h(*(const uint*)&r_h[2 * sub32 + 64 * p]);
            uint lo, hi;
            lo = __builtin_amdgcn_perm(mcb[p].x, mca[p].x, 0x05040100);
            hi = __builtin_amdgcn_perm(mcb[p].x, mca[p].x, 0x07060302);
            b[0] = __builtin_amdgcn_fdot2(u2h(lo), rp, b[0], false);
            b[1] = __builtin_amdgcn_fdot2(u2h(hi), rp, b[1], false);
            lo = __builtin_amdgcn_perm(mcb[p].y, mca[p].y, 0x05040100);
            hi = __builtin_amdgcn_perm(mcb[p].y, mca[p].y, 0x07060302);
            b[2] = __builtin_amdgcn_fdot2(u2h(lo), rp, b[2], false);
            b[3] = __builtin_amdgcn_fdot2(u2h(hi), rp, b[3], false);
            lo = __builtin_amdgcn_perm(mcb[p].z, mca[p].z, 0x05040100);
            hi = __builtin_amdgcn_perm(mcb[p].z, mca[p].z, 0x07060302);
            b[4] = __builtin_amdgcn_fdot2(u2h(lo), rp, b[4], false);
            b[5] = __builtin_amdgcn_fdot2(u2h(hi), rp, b[5], false);
            lo = __builtin_amdgcn_perm(mcb[p].w, mca[p].w, 0x05040100);
            hi = __builtin_amdgcn_perm(mcb[p].w, mca[p].w, 0x07060302);
            b[6] = __builtin_amdgcn_fdot2(u2h(lo), rp, b[6], false);
            b[7] = __builtin_amdgcn_fdot2(u2h(hi), rp, b[7], false);
        }
        // reduce-scatter over the 32-lane group: 8 cols -> 1 col/lane-quad
        float t0v, t1v, t2v, t3v;
        t0v = b4 ? b[0] : b[4]; t1v = b4 ? b[1] : b[5];
        t2v = b4 ? b[2] : b[6]; t3v = b4 ? b[3] : b[7];
        t0v = __shfl_xor(t0v, 16); t1v = __shfl_xor(t1v, 16);
        t2v = __shfl_xor(t2v, 16); t3v = __shfl_xor(t3v, 16);
        float k0 = (b4 ? b[4] : b[0]) + t0v;
        float k1 = (b4 ? b[5] : b[1]) + t1v;
        float k2 = (b4 ? b[6] : b[2]) + t2v;
        float k3 = (b4 ? b[7] : b[3]) + t3v;
        float u0 = b3 ? k0 : k2, u1 = b3 ? k1 : k3;
        u0 = __shfl_xor(u0, 8); u1 = __shfl_xor(u1, 8);
        float m0 = (b3 ? k2 : k0) + u0;
        float m1 = (b3 ? k3 : k1) + u1;
        float w0 = b2 ? m0 : m1;
        w0 = __shfl_xor(w0, 4);
        float s = (b2 ? m1 : m0) + w0;
        s += __shfl_xor(s, 1); s += __shfl_xor(s, 2);
        if (tid < 64) {      // Sr = sum r + r256
            float s2 = r_f[tid] + r_f[tid + 64] + r_f[tid + 128] + r_f[tid + 192];
            #pragma unroll
            for (int o = 32; o; o >>= 1) s2 += __shfl_down(s2, o);
            if (tid == 0) red[1] = s2 + r256;
        }
        if ((sub32 & 3) == 0) {
            int col = cg * 8 + b4 * 4 + b3 * 2 + b2;
            float v = 1.0f / (s + SVF * r256);
            c_f[col] = v; c_h[col] = __float2half(v);
        }
        __syncthreads();
    }

    // ======== fused final: out[row][d] = M0[row][d] * r[row] * c[d]
    float rv = r_f[row];
    #pragma unroll
    for (int j = 0; j < 8; ++j) {
        int cb = sub4 * 64 + j * 8;
        float4 ca  = *(const float4*)&c_f[cb];
        float4 cb4 = *(const float4*)&c_f[cb + 4];
        float2 f0 = h2f2u(mr[j].x), f1 = h2f2u(mr[j].y);
        float2 f2 = h2f2u(mr[j].z), f3 = h2f2u(mr[j].w);
        float4 o0, o1;
        o0.x = f0.x * rv * ca.x;  o0.y = f0.y * rv * ca.y;
        o0.z = f1.x * rv * ca.z;  o0.w = f1.y * rv * ca.w;
        o1.x = f2.x * rv * cb4.x; o1.y = f2.y * rv * cb4.y;
        o1.z = f3.x * rv * cb4.z; o1.w = f3.y * rv * cb4.w;
        *(float4*)&out[row * 256 + cb]     = o0;
        *(float4*)&out[row * 256 + cb + 4] = o1;
    }
}

extern "C" void kernel_launch(void* const* d_in, const int* in_sizes, int n_in,
                              void* d_out, int out_size, void* d_ws, size_t ws_size,
                              hipStream_t stream)
{
    const float* x       = (const float*)d_in[0];
    const float* coords  = (const float*)d_in[1];
    const float* co      = (const float*)d_in[2];
    const float* gt      = (const float*)d_in[3];
    const float* W_enc   = (const float*)d_in[5];
    const float* b_enc   = (const float*)d_in[6];
    const float* app_W1  = (const float*)d_in[7];
    const float* app_b1  = (const float*)d_in[8];
    const float* app_w2  = (const float*)d_in[9];
    const float* app_b2  = (const float*)d_in[10];
    const float* geo_W1  = (const float*)d_in[11];
    const float* geo_b1  = (const float*)d_in[12];
    const float* geo_w2  = (const float*)d_in[13];
    const float* geo_b2  = (const float*)d_in[14];
    const float* aff_w   = (const float*)d_in[15];
    const float* aff_b   = (const float*)d_in[16];
    const float* W_self  = (const float*)d_in[17];
    const float* W_nbr   = (const float*)d_in[18];
    const float* b_mp    = (const float*)d_in[19];
    const float* fin_w   = (const float*)d_in[20];
    const float* fin_b   = (const float*)d_in[21];
    float* out = (float*)d_out;

    // ---- workspace layout (round-6 proven aliasing: C45 aliases dead P)
    char* W = (char*)d_ws;
    float*  P     = (float*)(W + 0);         // [8][512][512] (dead after reduce)
    float*  h     = (float*)(W + 8388608);   // [512][512]
    float*  C45   = (float*)(W + 0);         // [512][1024] (Hn | Hs)  aliases P
    float*  C23   = (float*)(W + 2097152);   // [512][256]  (Aapp | Bapp)
    float*  ewT0  = (float*)(W + 2621440);   // [256 d][256 t]
    float*  ew2   = (float*)(W + 2883584);   // [256 t][256 d]
    float*  iou1  = (float*)(W + 3145728);   // [256][256]
    __half* Mh    = (__half*)(W + 3407872);  // [256][256] fp16
    float*  outm  = (float*)(W + 3670016);   // [512][512]

    // 1) encoder partials: P[z] = x @ W_enc[z-slice], z=0..7  (4 K-iters each)
    gemm64<0><<<dim3(8, 8, 8), 256, 0, stream>>>(x, nullptr, W_enc, nullptr, nullptr,
        nullptr, nullptr, P, nullptr);
    // 2) h = relu(sum_z P + b_enc)
    enc_reduce<<<256, 256, 0, stream>>>(P, b_enc, h);
    // 3) C45 = h@[Wnbr|Wself], C23 = h@[W1a|W1b]   (8 K-iters)
    gemm64<1><<<dim3(20, 8), 256, 0, stream>>>(h, nullptr, W_nbr, W_self, app_W1,
        nullptr, nullptr, C45, C23);
    // 4) per-edge ew + iou (geo MLP inlined) + gt copy + consts
    edge_geo_kernel<<<dim3(16, 16, 2), 256, 0, stream>>>(C23, coords, geo_W1, geo_b1,
        app_b1, app_w2, app_b2, geo_w2, geo_b2, aff_w, aff_b, co, gt, out,
        ewT0, ew2, iou1);
    // 5) outm = relu(ew@Hn + Hs + b_mp)   (4 K-iters)
    gemm64<2><<<dim3(8, 8), 256, 0, stream>>>(ew2, ewT0, C45, nullptr, nullptr,
        C45, b_mp, outm, nullptr);
    // 6) gram (BK=64, 8 iters) + norms + fin + M0(fp16)
    gram32<<<dim3(8, 8), 256, 0, stream>>>(outm, iou1, fin_w, fin_b, Mh);
    // 7) Sinkhorn + fused final output (register-resident M, fdot2)
    sinkhorn4f<<<1, 1024, 0, stream>>>(Mh, out);
}

// Round 15
// 77.856 us; speedup vs baseline: 1.0882x; 1.0882x over previous
//
#include <hip/hip_runtime.h>
#include <hip/hip_fp16.h>
#include <math.h>

#define EH   65536
#define LAMF 5.0f
#define SVF  0.36787944117144233f   // exp(-0.2*5) = exp(-1)

typedef __bf16 bf16x8 __attribute__((ext_vector_type(8)));
typedef float  f32x4  __attribute__((ext_vector_type(4)));
typedef _Float16 f16x2 __attribute__((ext_vector_type(2)));

__device__ __forceinline__ float sigmoidf_(float x) { return 1.0f / (1.0f + expf(-x)); }

__device__ __forceinline__ void cvt1(float v, ushort& h, ushort& l) {
    __bf16 bh = (__bf16)v;
    h = __builtin_bit_cast(ushort, bh);
    __bf16 bl = (__bf16)(v - (float)bh);
    l = __builtin_bit_cast(ushort, bl);
}

__device__ __forceinline__ f16x2 u2h(uint u) { return __builtin_bit_cast(f16x2, u); }
__device__ __forceinline__ float2 h2f2u(uint u) {
    __half2 h = __builtin_bit_cast(__half2, u);
    return __half22float2(h);
}

// ============ unified 64x64 MFMA GEMM, BK=64, split-bf16, reg-prefetch ======
// MODE 0: encoder partial  P[z] = x @ W_enc(k-slice, z=0..7)  grid(8,8,8), 4 iters
// MODE 1: C45|C23 fused    [h@Wnbr | h@Wself | h@W1a | h@W1b] grid(20,8),  8 iters
// MODE 2: agg + epilogue   outm = relu(ew@Hn + Hs + b_mp)     grid(8,8),   4 iters
#define LSTR2 72   // LDS row stride in ushorts (144B, 16B-aligned rows)
template<int MODE>
__global__ __launch_bounds__(256) void gemm64(
    const float* __restrict__ Aa, const float* __restrict__ Ab,
    const float* __restrict__ B0, const float* __restrict__ B1,
    const float* __restrict__ B2,
    const float* __restrict__ HsC45, const float* __restrict__ bmp,
    float* __restrict__ C0, float* __restrict__ C1)
{
    __shared__ ushort As_hi[64*LSTR2], As_lo[64*LSTR2];
    __shared__ ushort Bs_hi[64*LSTR2], Bs_lo[64*LSTR2];
    const int tid = threadIdx.x;
    const int row0 = blockIdx.y * 64;

    const float* Ap = Aa; int lda, arow0 = row0, ak = 0;
    const float* Bp; int ldb, kb = 0, bcol0;
    float* Cp; int ldc, ccol0;
    int KS;

    if (MODE == 0) {
        KS = 256; lda = 2048; ak = blockIdx.z * 256;
        Bp = B0; ldb = 512; kb = blockIdx.z * 256; bcol0 = blockIdx.x * 64;
        Cp = C0 + blockIdx.z * 262144; ldc = 512; ccol0 = bcol0;
    } else if (MODE == 1) {
        KS = 512; lda = 512;
        int cb = blockIdx.x;
        if (cb < 8)       { Bp=B0; ldb=512; kb=0;   bcol0=cb*64;        Cp=C0; ldc=1024; ccol0=cb*64; }
        else if (cb < 16) { Bp=B1; ldb=512; kb=0;   bcol0=(cb-8)*64;    Cp=C0; ldc=1024; ccol0=512+(cb-8)*64; }
        else if (cb < 18) { Bp=B2; ldb=128; kb=0;   bcol0=(cb-16)*64;   Cp=C1; ldc=256;  ccol0=(cb-16)*64; }
        else              { Bp=B2; ldb=128; kb=512; bcol0=(cb-18)*64;   Cp=C1; ldc=256;  ccol0=128+(cb-18)*64; }
    } else {
        KS = 256; lda = 256;
        if (row0 < 256) { Ap = Aa; arow0 = row0;       kb = 256; }
        else            { Ap = Ab; arow0 = row0 - 256; kb = 0; }
        Bp = B0; ldb = 1024; bcol0 = blockIdx.x * 64;
        Cp = C0; ldc = 512; ccol0 = bcol0;
    }

    // A-stage map: each thread 16 consecutive floats of one row (4 x float4)
    const int arow = tid >> 2, kq = (tid & 3) * 16;
    // B-stage map: 2 k-rows x 8 cols per thread
    const int kr = (tid & 31) * 2, nc0 = (tid >> 5) * 8;
    const float* aptr = Ap + (size_t)(arow0 + arow) * lda + ak + kq;
    const float* bptr = Bp + (size_t)(kb + kr) * ldb + bcol0 + nc0;

    f32x4 acc[2][2] = {};
    const int lane = tid & 63, w = tid >> 6;
    const int qr = (w >> 1) * 32, qc = (w & 1) * 32;
    const int fr = lane & 15, kg = (lane >> 4) * 8;

    float4 pa[4], pb[4];
    #pragma unroll
    for (int q = 0; q < 4; ++q) pa[q] = *(const float4*)(aptr + q * 4);
    pb[0] = *(const float4*)bptr;         pb[1] = *(const float4*)(bptr + 4);
    pb[2] = *(const float4*)(bptr + ldb); pb[3] = *(const float4*)(bptr + ldb + 4);

    for (int k0 = 0; k0 < KS; k0 += 64) {
        // ---- store staged tile (cvt fp32 -> hi/lo bf16)
        {
            #pragma unroll
            for (int q = 0; q < 4; ++q) {
                ushort4 h4, l4;
                cvt1(pa[q].x,h4.x,l4.x); cvt1(pa[q].y,h4.y,l4.y);
                cvt1(pa[q].z,h4.z,l4.z); cvt1(pa[q].w,h4.w,l4.w);
                *(ushort4*)&As_hi[arow*LSTR2 + kq + q*4] = h4;
                *(ushort4*)&As_lo[arow*LSTR2 + kq + q*4] = l4;
            }
            float r0[8] = {pb[0].x, pb[0].y, pb[0].z, pb[0].w,
                           pb[1].x, pb[1].y, pb[1].z, pb[1].w};
            float r1[8] = {pb[2].x, pb[2].y, pb[2].z, pb[2].w,
                           pb[3].x, pb[3].y, pb[3].z, pb[3].w};
            #pragma unroll
            for (int j = 0; j < 8; ++j) {
                ushort ha, la, hb, lb;
                cvt1(r0[j], ha, la); cvt1(r1[j], hb, lb);
                *(uint*)&Bs_hi[(nc0+j)*LSTR2 + kr] = (uint)ha | ((uint)hb << 16);
                *(uint*)&Bs_lo[(nc0+j)*LSTR2 + kr] = (uint)la | ((uint)lb << 16);
            }
        }
        __syncthreads();
        if (k0 + 64 < KS) {   // prefetch next tile (overlaps MFMA + barrier)
            #pragma unroll
            for (int q = 0; q < 4; ++q) pa[q] = *(const float4*)(aptr + k0 + 64 + q * 4);
            const float* bp2 = bptr + (size_t)(k0 + 64) * ldb;
            pb[0] = *(const float4*)bp2;         pb[1] = *(const float4*)(bp2 + 4);
            pb[2] = *(const float4*)(bp2 + ldb); pb[3] = *(const float4*)(bp2 + ldb + 4);
        }
        #pragma unroll
        for (int kk = 0; kk < 2; ++kk) {
            bf16x8 ah[2], al[2], bh[2], bl[2];
            #pragma unroll
            for (int m = 0; m < 2; ++m) {
                int r = (qr + m*16 + fr) * LSTR2 + kg + kk * 32;
                ah[m] = *(const bf16x8*)&As_hi[r];
                al[m] = *(const bf16x8*)&As_lo[r];
            }
            #pragma unroll
            for (int n = 0; n < 2; ++n) {
                int r = (qc + n*16 + fr) * LSTR2 + kg + kk * 32;
                bh[n] = *(const bf16x8*)&Bs_hi[r];
                bl[n] = *(const bf16x8*)&Bs_lo[r];
            }
            #pragma unroll
            for (int m = 0; m < 2; ++m)
                #pragma unroll
                for (int n = 0; n < 2; ++n) {
                    acc[m][n] = __builtin_amdgcn_mfma_f32_16x16x32_bf16(ah[m], bh[n], acc[m][n], 0, 0, 0);
                    acc[m][n] = __builtin_amdgcn_mfma_f32_16x16x32_bf16(ah[m], bl[n], acc[m][n], 0, 0, 0);
                    acc[m][n] = __builtin_amdgcn_mfma_f32_16x16x32_bf16(al[m], bh[n], acc[m][n], 0, 0, 0);
                }
        }
        __syncthreads();
    }

    const int rbase = (lane >> 4) * 4;
    #pragma unroll
    for (int m = 0; m < 2; ++m)
        #pragma unroll
        for (int n = 0; n < 2; ++n)
            #pragma unroll
            for (int r = 0; r < 4; ++r) {
                int gr = row0 + qr + m*16 + rbase + r;
                int gc = ccol0 + qc + n*16 + (lane & 15);
                float v = acc[m][n][r];
                if (MODE == 2) {
                    v += HsC45[(size_t)gr * 1024 + 512 + gc] + bmp[gc];
                    v = fmaxf(v, 0.f);
                }
                Cp[(size_t)gr * ldc + gc] = v;
            }
}

// ============ encoder split-K reduce: h = relu(sum_z P[z] + bias) ===========
__global__ __launch_bounds__(256) void enc_reduce(const float* __restrict__ P,
    const float* __restrict__ bias, float* __restrict__ h)
{
    int e = (blockIdx.x * 256 + threadIdx.x) * 4;
    int col = e & 511;
    float4 s = *(const float4*)&P[e];
    #pragma unroll
    for (int z = 1; z < 8; ++z) {
        float4 v = *(const float4*)&P[e + z * 262144];
        s.x += v.x; s.y += v.y; s.z += v.z; s.w += v.w;
    }
    float4 b = *(const float4*)&bias[col];
    float4 o;
    o.x = fmaxf(s.x + b.x, 0.f);
    o.y = fmaxf(s.y + b.y, 0.f);
    o.z = fmaxf(s.z + b.z, 0.f);
    o.w = fmaxf(s.w + b.w, 0.f);
    *(float4*)&h[e] = o;
}

// ============ per-edge ew + iou (geo MLP inlined, b128 LDS reads) ===========
__global__ __launch_bounds__(256) void edge_geo_kernel(
    const float* __restrict__ C23, const float* __restrict__ coords,
    const float* __restrict__ geo_W1, const float* __restrict__ geo_b1,
    const float* __restrict__ app_b1, const float* __restrict__ app_w2,
    const float* __restrict__ app_b2, const float* __restrict__ geo_w2,
    const float* __restrict__ geo_b2, const float* __restrict__ aff_w,
    const float* __restrict__ aff_b, const float* __restrict__ co,
    const float* __restrict__ gt, float* __restrict__ outp,
    float* __restrict__ ewT0, float* __restrict__ ew2, float* __restrict__ iou1)
{
    __shared__ __align__(16) float sA[16][132], sB[16][132];
    __shared__ __align__(16) float sGA[16][68], sGB[16][68];
    __shared__ __align__(16) float sw2[128], sgw2[64];
    __shared__ float sgw[8][64], sgb[64], scs[16][4], scd[16][4];
    const int tid = threadIdx.x;
    const int half = blockIdx.z;
    const int t0 = blockIdx.y * 16, d0 = blockIdx.x * 16;
    const int sbase = half ? (256 + d0) : t0;   // source-node rows
    const int dbase = half ? t0 : (256 + d0);   // dest-node rows

    // fold gt-copy + scalar consts into half=1 blocks (independent early work)
    if (half == 1) {
        int bid = blockIdx.y * 16 + blockIdx.x;     // 0..255
        if (tid < 64) {
            int o = bid * 256 + tid * 4;
            *(float4*)&outp[EH + o] = *(const float4*)&gt[o];
        }
        if (bid == 0 && tid == 64) {
            outp[2 * EH]     = 256.0f;
            outp[2 * EH + 1] = 256.0f;
        }
    }

    for (int i = tid; i < 16 * 32; i += 256) {
        int rr = i >> 5, c4 = (i & 31) << 2;
        float4 va = *(const float4*)&C23[(sbase + rr) * 256 + c4];
        sA[rr][c4] = va.x; sA[rr][c4+1] = va.y; sA[rr][c4+2] = va.z; sA[rr][c4+3] = va.w;
        float4 vb = *(const float4*)&C23[(dbase + rr) * 256 + 128 + c4];
        float4 b1 = *(const float4*)&app_b1[c4];
        sB[rr][c4] = vb.x + b1.x; sB[rr][c4+1] = vb.y + b1.y;
        sB[rr][c4+2] = vb.z + b1.z; sB[rr][c4+3] = vb.w + b1.w;
    }
    for (int i = tid; i < 512; i += 256) sgw[i >> 6][i & 63] = geo_W1[i];
    if (tid < 64) sgb[tid] = geo_b1[tid];
    else if (tid < 192) sw2[tid - 64] = app_w2[tid - 64];
    else sgw2[tid - 192] = geo_w2[tid - 192];
    if (tid < 64) scs[tid >> 2][tid & 3] = coords[(sbase + (tid >> 2)) * 4 + (tid & 3)];
    else if (tid < 128) { int i = tid - 64; scd[i >> 2][i & 3] = coords[(dbase + (i >> 2)) * 4 + (i & 3)]; }
    __syncthreads();
    for (int v = tid; v < 2048; v += 256) {
        int hh = v >> 10, rr = (v >> 6) & 15, j = v & 63;
        if (hh == 0) {
            sGA[rr][j] = scs[rr][0]*sgw[0][j] + scs[rr][1]*sgw[1][j]
                       + scs[rr][2]*sgw[2][j] + scs[rr][3]*sgw[3][j] + sgb[j];
        } else {
            sGB[rr][j] = scd[rr][0]*sgw[4][j] + scd[rr][1]*sgw[5][j]
                       + scd[rr][2]*sgw[6][j] + scd[rr][3]*sgw[7][j];
        }
    }
    __syncthreads();
    const int tx = tid & 15, ty = tid >> 4;
    const int si = half ? tx : ty;
    const int di = half ? ty : tx;
    float acc1 = 0.f;
    #pragma unroll
    for (int j4 = 0; j4 < 128; j4 += 4) {
        float4 a = *(const float4*)&sA[si][j4];
        float4 b = *(const float4*)&sB[di][j4];
        float4 wv = *(const float4*)&sw2[j4];
        acc1 += fmaxf(a.x + b.x, 0.f) * wv.x + fmaxf(a.y + b.y, 0.f) * wv.y
              + fmaxf(a.z + b.z, 0.f) * wv.z + fmaxf(a.w + b.w, 0.f) * wv.w;
    }
    float x1 = sigmoidf_(acc1 + app_b2[0]);
    float acc2 = 0.f;
    #pragma unroll
    for (int j4 = 0; j4 < 64; j4 += 4) {
        float4 a = *(const float4*)&sGA[si][j4];
        float4 b = *(const float4*)&sGB[di][j4];
        float4 wv = *(const float4*)&sgw2[j4];
        acc2 += fmaxf(a.x + b.x, 0.f) * wv.x + fmaxf(a.y + b.y, 0.f) * wv.y
              + fmaxf(a.z + b.z, 0.f) * wv.z + fmaxf(a.w + b.w, 0.f) * wv.w;
    }
    float x2 = sigmoidf_(acc2 + geo_b2[0]);
    float e = sigmoidf_(x1 * aff_w[0] + x2 * aff_w[1] + aff_b[0]);
    const int t = t0 + ty, d = d0 + tx;
    if (half) ew2[t * 256 + d] = e;
    else      ewT0[d * 256 + t] = e;
    if (half == 0) {
        float4 a = *(const float4*)&co[t * 4];
        float4 b = *(const float4*)&co[(256 + d) * 4];
        float ltx = fmaxf(a.x, b.x), lty = fmaxf(a.y, b.y);
        float rbx = fminf(a.z, b.z), rby = fminf(a.w, b.w);
        float w  = fmaxf(rbx - ltx, 0.f), hh = fmaxf(rby - lty, 0.f);
        float inter = w * hh;
        float areaA = (a.z - a.x) * (a.w - a.y);
        float areaB = (b.z - b.x) * (b.w - b.y);
        iou1[t * 256 + d] = inter / (areaA + areaB - inter + 1e-6f);
    }
}

// ============ gram 32x32, BK=64 (8 iters), norms + fin/exp epilogue =========
__global__ __launch_bounds__(256) void gram32(const float* __restrict__ outm,
    const float* __restrict__ iou, const float* __restrict__ finw,
    const float* __restrict__ finb, __half* __restrict__ Mh)
{
    __shared__ ushort As_hi[32*LSTR2], As_lo[32*LSTR2];
    __shared__ ushort Bs_hi[32*LSTR2], Bs_lo[32*LSTR2];
    __shared__ float snA[32], snB[32];
    const int tid = threadIdx.x;
    const int t0 = blockIdx.y * 32, d0 = blockIdx.x * 32;
    const float* Asrc = outm;
    const float* Bsrc = outm + (size_t)256 * 512;

    // stage map: each thread 8 consecutive floats of one row (2 x float4)
    const int arow = tid >> 3, kq = (tid & 7) * 8;
    const float* aptr = Asrc + (size_t)(t0 + arow) * 512 + kq;
    const float* bptr = Bsrc + (size_t)(d0 + arow) * 512 + kq;

    f32x4 acc = {};
    float ssA = 0.f, ssB = 0.f;
    const int lane = tid & 63, w = tid >> 6;
    const int qr = (w >> 1) * 16, qc = (w & 1) * 16;
    const int fr = lane & 15, kg = (lane >> 4) * 8;

    float4 pa0 = *(const float4*)aptr, pa1 = *(const float4*)(aptr + 4);
    float4 pb0 = *(const float4*)bptr, pb1 = *(const float4*)(bptr + 4);

    for (int k0 = 0; k0 < 512; k0 += 64) {
        ssA += pa0.x*pa0.x + pa0.y*pa0.y + pa0.z*pa0.z + pa0.w*pa0.w
             + pa1.x*pa1.x + pa1.y*pa1.y + pa1.z*pa1.z + pa1.w*pa1.w;
        ssB += pb0.x*pb0.x + pb0.y*pb0.y + pb0.z*pb0.z + pb0.w*pb0.w
             + pb1.x*pb1.x + pb1.y*pb1.y + pb1.z*pb1.z + pb1.w*pb1.w;
        {
            ushort4 h4, l4;
            cvt1(pa0.x,h4.x,l4.x); cvt1(pa0.y,h4.y,l4.y); cvt1(pa0.z,h4.z,l4.z); cvt1(pa0.w,h4.w,l4.w);
            *(ushort4*)&As_hi[arow*LSTR2 + kq] = h4;
            *(ushort4*)&As_lo[arow*LSTR2 + kq] = l4;
            cvt1(pa1.x,h4.x,l4.x); cvt1(pa1.y,h4.y,l4.y); cvt1(pa1.z,h4.z,l4.z); cvt1(pa1.w,h4.w,l4.w);
            *(ushort4*)&As_hi[arow*LSTR2 + kq + 4] = h4;
            *(ushort4*)&As_lo[arow*LSTR2 + kq + 4] = l4;
            cvt1(pb0.x,h4.x,l4.x); cvt1(pb0.y,h4.y,l4.y); cvt1(pb0.z,h4.z,l4.z); cvt1(pb0.w,h4.w,l4.w);
            *(ushort4*)&Bs_hi[arow*LSTR2 + kq] = h4;
            *(ushort4*)&Bs_lo[arow*LSTR2 + kq] = l4;
            cvt1(pb1.x,h4.x,l4.x); cvt1(pb1.y,h4.y,l4.y); cvt1(pb1.z,h4.z,l4.z); cvt1(pb1.w,h4.w,l4.w);
            *(ushort4*)&Bs_hi[arow*LSTR2 + kq + 4] = h4;
            *(ushort4*)&Bs_lo[arow*LSTR2 + kq + 4] = l4;
        }
        __syncthreads();
        if (k0 + 64 < 512) {
            pa0 = *(const float4*)(aptr + k0 + 64);
            pa1 = *(const float4*)(aptr + k0 + 68);
            pb0 = *(const float4*)(bptr + k0 + 64);
            pb1 = *(const float4*)(bptr + k0 + 68);
        }
        #pragma unroll
        for (int kk = 0; kk < 2; ++kk) {
            bf16x8 ah, al, bh, bl;
            {
                int r = (qr + fr) * LSTR2 + kg + kk * 32;
                ah = *(const bf16x8*)&As_hi[r]; al = *(const bf16x8*)&As_lo[r];
            }
            {
                int r = (qc + fr) * LSTR2 + kg + kk * 32;
                bh = *(const bf16x8*)&Bs_hi[r]; bl = *(const bf16x8*)&Bs_lo[r];
            }
            acc = __builtin_amdgcn_mfma_f32_16x16x32_bf16(ah, bh, acc, 0, 0, 0);
            acc = __builtin_amdgcn_mfma_f32_16x16x32_bf16(ah, bl, acc, 0, 0, 0);
            acc = __builtin_amdgcn_mfma_f32_16x16x32_bf16(al, bh, acc, 0, 0, 0);
        }
        __syncthreads();
    }
    // reduce sumsq across the 8 threads sharing a row (consecutive lanes)
    ssA += __shfl_xor(ssA, 1); ssA += __shfl_xor(ssA, 2); ssA += __shfl_xor(ssA, 4);
    ssB += __shfl_xor(ssB, 1); ssB += __shfl_xor(ssB, 2); ssB += __shfl_xor(ssB, 4);
    if ((tid & 7) == 0) { snA[arow] = ssA; snB[arow] = ssB; }
    __syncthreads();
    const float fw0 = finw[0], fw1 = finw[1], fb = finb[0];
    const int rbase = (lane >> 4) * 4, lc = qc + (lane & 15);
    #pragma unroll
    for (int r = 0; r < 4; ++r) {
        int lr = qr + rbase + r;
        float na = fmaxf(sqrtf(snA[lr]), 1e-6f);
        float nb = fmaxf(sqrtf(snB[lc]), 1e-6f);
        int t = t0 + lr, d = d0 + lc;
        float cosv = acc[r] / (na * nb);
        float fin = sigmoidf_(cosv * fw0 + iou[t * 256 + d] * fw1 + fb);
        Mh[t * 256 + d] = __float2half(expf(fin * LAMF));
    }
}

// ============ Sinkhorn4: M fp16 fully register-resident, v_dot2_f32_f16 =====
__global__ __launch_bounds__(1024, 4) void sinkhorn4(const __half* __restrict__ Mh,
    float* __restrict__ gr, float* __restrict__ gc)
{
    __shared__ float r_f[256], c_f[256], red[16];
    __shared__ __half r_h[256], c_h[256];
    const int tid = threadIdx.x;
    const int row = tid >> 2, sub4 = tid & 3;
    const int cg = tid >> 5, sub32 = tid & 31;

    const uint4* gm = (const uint4*)Mh;            // [256 rows][32 uint4]
    uint4 mr[8];                                   // row-view
    #pragma unroll
    for (int j = 0; j < 8; ++j) mr[j] = gm[row * 32 + sub4 * 8 + j];
    uint4 mca[4], mcb[4];                          // col-view row-pairs
    #pragma unroll
    for (int p = 0; p < 4; ++p) {
        int rp = 2 * sub32 + 64 * p;
        mca[p] = gm[rp * 32 + cg];
        mcb[p] = gm[(rp + 1) * 32 + cg];
    }
    if (tid < 256) { c_f[tid] = 1.0f; c_h[tid] = __float2half(1.0f); }
    if (tid == 0) red[1] = 1.0f / SVF;             // makes c256 = 1 at it=0
    __syncthreads();

    const int b4 = (sub32 >> 4) & 1, b3 = (sub32 >> 3) & 1, b2 = (sub32 >> 2) & 1;

    for (int it = 0; it < 8; ++it) {
        // ======== ROW phase: r[t] = 1/(sum_d M[t][d] c[d] + SVF*c256)
        float c256 = 1.0f / (SVF * red[1]);
        float a0 = 0.f, a1 = 0.f, a2 = 0.f, a3 = 0.f;
        {
            uint4 cu[4];
            #pragma unroll
            for (int j = 0; j < 4; ++j) cu[j] = *(const uint4*)&c_h[sub4 * 64 + j * 8];
            #pragma unroll
            for (int j = 0; j < 4; ++j) {
                a0 = __builtin_amdgcn_fdot2(u2h(mr[j].x), u2h(cu[j].x), a0, false);
                a1 = __builtin_amdgcn_fdot2(u2h(mr[j].y), u2h(cu[j].y), a1, false);
                a2 = __builtin_amdgcn_fdot2(u2h(mr[j].z), u2h(cu[j].z), a2, false);
                a3 = __builtin_amdgcn_fdot2(u2h(mr[j].w), u2h(cu[j].w), a3, false);
            }
            #pragma unroll
            for (int j = 0; j < 4; ++j) cu[j] = *(const uint4*)&c_h[sub4 * 64 + 32 + j * 8];
            #pragma unroll
            for (int j = 0; j < 4; ++j) {
                a0 = __builtin_amdgcn_fdot2(u2h(mr[4+j].x), u2h(cu[j].x), a0, false);
                a1 = __builtin_amdgcn_fdot2(u2h(mr[4+j].y), u2h(cu[j].y), a1, false);
                a2 = __builtin_amdgcn_fdot2(u2h(mr[4+j].z), u2h(cu[j].z), a2, false);
                a3 = __builtin_amdgcn_fdot2(u2h(mr[4+j].w), u2h(cu[j].w), a3, false);
            }
        }
        float acc = (a0 + a1) + (a2 + a3);
        acc += __shfl_xor(acc, 1); acc += __shfl_xor(acc, 2);
        if (tid < 64) {      // Sc = sum c + c256
            float s = c_f[tid] + c_f[tid + 64] + c_f[tid + 128] + c_f[tid + 192];
            #pragma unroll
            for (int o = 32; o; o >>= 1) s += __shfl_down(s, o);
            if (tid == 0) red[0] = s + c256;
        }
        if (sub4 == 0) {
            float v = 1.0f / (acc + SVF * c256);
            r_f[row] = v; r_h[row] = __float2half(v);
        }
        __syncthreads();

        // ======== COL phase: c[d] = 1/(sum_t M[t][d] r[t] + SVF*r256)
        float r256 = 1.0f / (SVF * red[0]);
        float b[8] = {0.f,0.f,0.f,0.f,0.f,0.f,0.f,0.f};
        #pragma unroll
        for (int p = 0; p < 4; ++p) {
            f16x2 rp = u2h(*(const uint*)&r_h[2 * sub32 + 64 * p]);
            uint lo, hi;
            lo = __builtin_amdgcn_perm(mcb[p].x, mca[p].x, 0x05040100);
            hi = __builtin_amdgcn_perm(mcb[p].x, mca[p].x, 0x07060302);
            b[0] = __builtin_amdgcn_fdot2(u2h(lo), rp, b[0], false);
            b[1] = __builtin_amdgcn_fdot2(u2h(hi), rp, b[1], false);
            lo = __builtin_amdgcn_perm(mcb[p].y, mca[p].y, 0x05040100);
            hi = __builtin_amdgcn_perm(mcb[p].y, mca[p].y, 0x07060302);
            b[2] = __builtin_amdgcn_fdot2(u2h(lo), rp, b[2], false);
            b[3] = __builtin_amdgcn_fdot2(u2h(hi), rp, b[3], false);
            lo = __builtin_amdgcn_perm(mcb[p].z, mca[p].z, 0x05040100);
            hi = __builtin_amdgcn_perm(mcb[p].z, mca[p].z, 0x07060302);
            b[4] = __builtin_amdgcn_fdot2(u2h(lo), rp, b[4], false);
            b[5] = __builtin_amdgcn_fdot2(u2h(hi), rp, b[5], false);
            lo = __builtin_amdgcn_perm(mcb[p].w, mca[p].w, 0x05040100);
            hi = __builtin_amdgcn_perm(mcb[p].w, mca[p].w, 0x07060302);
            b[6] = __builtin_amdgcn_fdot2(u2h(lo), rp, b[6], false);
            b[7] = __builtin_amdgcn_fdot2(u2h(hi), rp, b[7], false);
        }
        // reduce-scatter over the 32-lane group: 8 cols -> 1 col/lane-quad
        float t0v, t1v, t2v, t3v;
        t0v = b4 ? b[0] : b[4]; t1v = b4 ? b[1] : b[5];
        t2v = b4 ? b[2] : b[6]; t3v = b4 ? b[3] : b[7];
        t0v = __shfl_xor(t0v, 16); t1v = __shfl_xor(t1v, 16);
        t2v = __shfl_xor(t2v, 16); t3v = __shfl_xor(t3v, 16);
        float k0 = (b4 ? b[4] : b[0]) + t0v;
        float k1 = (b4 ? b[5] : b[1]) + t1v;
        float k2 = (b4 ? b[6] : b[2]) + t2v;
        float k3 = (b4 ? b[7] : b[3]) + t3v;
        float u0 = b3 ? k0 : k2, u1 = b3 ? k1 : k3;
        u0 = __shfl_xor(u0, 8); u1 = __shfl_xor(u1, 8);
        float m0 = (b3 ? k2 : k0) + u0;
        float m1 = (b3 ? k3 : k1) + u1;
        float w0 = b2 ? m0 : m1;
        w0 = __shfl_xor(w0, 4);
        float s = (b2 ? m1 : m0) + w0;
        s += __shfl_xor(s, 1); s += __shfl_xor(s, 2);
        if (tid < 64) {      // Sr = sum r + r256
            float s2 = r_f[tid] + r_f[tid + 64] + r_f[tid + 128] + r_f[tid + 192];
            #pragma unroll
            for (int o = 32; o; o >>= 1) s2 += __shfl_down(s2, o);
            if (tid == 0) red[1] = s2 + r256;
        }
        if ((sub32 & 3) == 0) {
            int col = cg * 8 + b4 * 4 + b3 * 2 + b2;
            float v = 1.0f / (s + SVF * r256);
            c_f[col] = v; c_h[col] = __float2half(v);
        }
        __syncthreads();
    }
    if (tid < 256) { gr[tid] = r_f[tid]; gc[tid] = c_f[tid]; }
}

// ============ final output assembly (M part only) ===========================
__global__ __launch_bounds__(256) void final_kernel(const __half* __restrict__ Mh,
    const float* __restrict__ r, const float* __restrict__ c,
    float* __restrict__ out)
{
    const int bid = blockIdx.x, tid = threadIdx.x;
    int k = bid * 256 + tid;
    out[k] = __half2float(Mh[k]) * r[bid] * c[tid];
}

extern "C" void kernel_launch(void* const* d_in, const int* in_sizes, int n_in,
                              void* d_out, int out_size, void* d_ws, size_t ws_size,
                              hipStream_t stream)
{
    const float* x       = (const float*)d_in[0];
    const float* coords  = (const float*)d_in[1];
    const float* co      = (const float*)d_in[2];
    const float* gt      = (const float*)d_in[3];
    const float* W_enc   = (const float*)d_in[5];
    const float* b_enc   = (const float*)d_in[6];
    const float* app_W1  = (const float*)d_in[7];
    const float* app_b1  = (const float*)d_in[8];
    const float* app_w2  = (const float*)d_in[9];
    const float* app_b2  = (const float*)d_in[10];
    const float* geo_W1  = (const float*)d_in[11];
    const float* geo_b1  = (const float*)d_in[12];
    const float* geo_w2  = (const float*)d_in[13];
    const float* geo_b2  = (const float*)d_in[14];
    const float* aff_w   = (const float*)d_in[15];
    const float* aff_b   = (const float*)d_in[16];
    const float* W_self  = (const float*)d_in[17];
    const float* W_nbr   = (const float*)d_in[18];
    const float* b_mp    = (const float*)d_in[19];
    const float* fin_w   = (const float*)d_in[20];
    const float* fin_b   = (const float*)d_in[21];
    float* out = (float*)d_out;

    // ---- workspace layout (round-6 proven aliasing: C45 aliases dead P)
    char* W = (char*)d_ws;
    float*  P     = (float*)(W + 0);         // [8][512][512] (dead after reduce)
    float*  h     = (float*)(W + 8388608);   // [512][512]
    float*  C45   = (float*)(W + 0);         // [512][1024] (Hn | Hs)  aliases P
    float*  C23   = (float*)(W + 2097152);   // [512][256]  (Aapp | Bapp)
    float*  ewT0  = (float*)(W + 2621440);   // [256 d][256 t]
    float*  ew2   = (float*)(W + 2883584);   // [256 t][256 d]
    float*  iou1  = (float*)(W + 3145728);   // [256][256]
    __half* Mh    = (__half*)(W + 3407872);  // [256][256] fp16
    float*  grv   = (float*)(W + 3538944);
    float*  gcv   = (float*)(W + 3543040);
    float*  outm  = (float*)(W + 3670016);   // [512][512]

    // 1) encoder partials: P[z] = x @ W_enc[z-slice], z=0..7  (4 K-iters each)
    gemm64<0><<<dim3(8, 8, 8), 256, 0, stream>>>(x, nullptr, W_enc, nullptr, nullptr,
        nullptr, nullptr, P, nullptr);
    // 2) h = relu(sum_z P + b_enc)
    enc_reduce<<<256, 256, 0, stream>>>(P, b_enc, h);
    // 3) C45 = h@[Wnbr|Wself], C23 = h@[W1a|W1b]   (8 K-iters)
    gemm64<1><<<dim3(20, 8), 256, 0, stream>>>(h, nullptr, W_nbr, W_self, app_W1,
        nullptr, nullptr, C45, C23);
    // 4) per-edge ew + iou (geo MLP inlined) + gt copy + consts
    edge_geo_kernel<<<dim3(16, 16, 2), 256, 0, stream>>>(C23, coords, geo_W1, geo_b1,
        app_b1, app_w2, app_b2, geo_w2, geo_b2, aff_w, aff_b, co, gt, out,
        ewT0, ew2, iou1);
    // 5) outm = relu(ew@Hn + Hs + b_mp)   (4 K-iters)
    gemm64<2><<<dim3(8, 8), 256, 0, stream>>>(ew2, ewT0, C45, nullptr, nullptr,
        C45, b_mp, outm, nullptr);
    // 6) gram (BK=64, 8 iters) + norms + fin + M0(fp16)
    gram32<<<dim3(8, 8), 256, 0, stream>>>(outm, iou1, fin_w, fin_b, Mh);
    // 7) Sinkhorn scale vectors (register-resident M, fdot2)
    sinkhorn4<<<1, 1024, 0, stream>>>(Mh, grv, gcv);
    // 8) final output assembly (M part)
    final_kernel<<<256, 256, 0, stream>>>(Mh, grv, gcv, out);
}